// Round 5
// baseline (398.819 us; speedup 1.0000x reference)
//
#include <hip/hip_runtime.h>
#include <math.h>

#define B_SZ    16384
#define NNZ_PER 32
#define NNZ     (B_SZ * NNZ_PER)
#define FT_OUT  512
#define F_BIG   49152
#define F_SMALL 768
#define MODV    640

// prep grid partition
#define TP_A     6144              // W_ft 64x64 tiles: 8 ot x 768 ct
#define TP_B     80                // W_fft 64x64 tiles: 8 ot x 10 ct
#define HISTB    512
#define PREP_GRID (TP_A + TP_B + HISTB)

// native clang vectors for nontemporal builtins (HIP_vector_type is rejected)
typedef unsigned int nuint4 __attribute__((ext_vector_type(4)));
typedef float        nfloat4 __attribute__((ext_vector_type(4)));

// ---------------------------------------------------------------------------
// ws layout:
//   Wt_bf   : F_BIG*FT_OUT ushort      48 MB  transposed big weight, bf16
//   Wfft_t  : MODV*FT_OUT float        1.3 MB transposed small weight (fp32)
//   H       : 2*MODV*MODV float        3.3 MB weighted histograms
//   fft_acc : 2*MODV*FT_OUT float      2.6 MB H @ Wfft^T (summed, per side)
// ---------------------------------------------------------------------------

__device__ __forceinline__ unsigned short f32_to_bf16_rne(float f) {
    union { float f; unsigned int u; } v; v.f = f;
    unsigned int u = v.u;
    return (unsigned short)((u + 0x7fffu + ((u >> 16) & 1u)) >> 16);
}

__device__ __forceinline__ void unpack_bf16x2(unsigned int u, float& lo, float& hi) {
    union { unsigned int i; float f; } a, b;
    a.i = u << 16;            // even element
    b.i = u & 0xffff0000u;    // odd element
    lo = a.f; hi = b.f;
}

__device__ __forceinline__ float clip01(float x) {
    return fminf(fmaxf(x, 0.0f), 1.0f);
}

// One kernel for all prologue work: transpose+bf16-quantize W_ft (nontemporal
// stores so dirty lines don't writeback during main), transpose W_fft, and
// the mod-640 weighted histogram.
__global__ __launch_bounds__(256)
void prep_kernel(const float* __restrict__ W_ft, const float* __restrict__ W_fft,
                 const int* __restrict__ stm, const int* __restrict__ nstm,
                 const float* __restrict__ vals,
                 unsigned short* __restrict__ Wt, float* __restrict__ Wfft_t,
                 float* __restrict__ H) {
    int b = blockIdx.x;
    int tid = threadIdx.x;
    if (b < TP_A + TP_B) {
        __shared__ float tile[64][65];
        const bool isA = b < TP_A;
        int b2 = isA ? b : b - TP_A;
        int nct = isA ? (F_BIG / 64) : (MODV / 64);
        int rowlen = isA ? F_BIG : F_SMALL;
        const float* src = isA ? W_ft : W_fft;
        int ot = b2 / nct, ct = b2 % nct;
        int c0 = ct * 64, o0 = ot * 64;
        int rr = tid >> 4, c4 = (tid & 15) * 4;
#pragma unroll
        for (int it = 0; it < 4; it++) {
            int oo = rr + it * 16;
            float4 f = *(const float4*)(src + (size_t)(o0 + oo) * rowlen + c0 + c4);
            tile[oo][c4 + 0] = f.x; tile[oo][c4 + 1] = f.y;
            tile[oo][c4 + 2] = f.z; tile[oo][c4 + 3] = f.w;
        }
        __syncthreads();
        if (isA) {
            // 64 c-rows x 64 bf16 = 8 uint4 lanes per row
#pragma unroll
            for (int it = 0; it < 2; it++) {
                int idx = tid + it * 256;
                int cc = idx >> 3, g = idx & 7;
                nuint4 pk;
                {
                    unsigned int lo, hi;
                    lo = f32_to_bf16_rne(tile[g * 8 + 0][cc]);
                    hi = f32_to_bf16_rne(tile[g * 8 + 1][cc]);
                    pk.x = lo | (hi << 16);
                    lo = f32_to_bf16_rne(tile[g * 8 + 2][cc]);
                    hi = f32_to_bf16_rne(tile[g * 8 + 3][cc]);
                    pk.y = lo | (hi << 16);
                    lo = f32_to_bf16_rne(tile[g * 8 + 4][cc]);
                    hi = f32_to_bf16_rne(tile[g * 8 + 5][cc]);
                    pk.z = lo | (hi << 16);
                    lo = f32_to_bf16_rne(tile[g * 8 + 6][cc]);
                    hi = f32_to_bf16_rne(tile[g * 8 + 7][cc]);
                    pk.w = lo | (hi << 16);
                }
                __builtin_nontemporal_store(pk,
                    (nuint4*)(Wt + (size_t)(c0 + cc) * FT_OUT + o0 + g * 8));
            }
        } else {
            // 64 c-rows x 64 fp32 = 16 float4 lanes per row
#pragma unroll
            for (int it = 0; it < 4; it++) {
                int idx = tid + it * 256;
                int cc = idx >> 4, g = idx & 15;
                nfloat4 v;
                v.x = tile[g * 4 + 0][cc]; v.y = tile[g * 4 + 1][cc];
                v.z = tile[g * 4 + 2][cc]; v.w = tile[g * 4 + 3][cc];
                __builtin_nontemporal_store(v,
                    (nfloat4*)(Wfft_t + (size_t)(c0 + cc) * FT_OUT + o0 + g * 4));
            }
        }
    } else {
        int i0 = (b - TP_A - TP_B) * 256 + tid;
        for (int e = i0; e < 2 * NNZ; e += HISTB * 256) {
            int side = (e >= NNZ) ? 1 : 0;
            int j = e - side * NNZ;
            const int* arr = side ? nstm : stm;
            int r = arr[j] % MODV;          // row indices at offset 0
            int c = arr[NNZ + j] % MODV;    // col indices at offset NNZ
            atomicAdd(&H[(size_t)side * MODV * MODV + r * MODV + c], vals[j]);
        }
    }
}

// acc[side][s][o] = sum_cc H[side][s][cc] * Wfft_t[cc][o]
// grid = 2 sides x 160 s-tiles (4 rows each) = 320 blocks, full cc loop
__global__ __launch_bounds__(512)
void fft_gemm(const float* __restrict__ H, const float* __restrict__ Wfft_t,
              float* __restrict__ acc) {
    __shared__ float hs[4][MODV];
    int o = threadIdx.x;                 // 0..511
    int b = blockIdx.x;
    int side = b / 160;
    int s0   = (b % 160) * 4;
    const float* Hs = H + (size_t)side * MODV * MODV;
    for (int t = threadIdx.x; t < 4 * MODV; t += 512) {
        int j = t / MODV, cc = t - j * MODV;
        hs[j][cc] = Hs[(size_t)(s0 + j) * MODV + cc];
    }
    __syncthreads();
    float a[4] = {0, 0, 0, 0};
    for (int cc = 0; cc < MODV; cc++) {
        float wv = Wfft_t[(size_t)cc * FT_OUT + o];
#pragma unroll
        for (int j = 0; j < 4; j++) a[j] += hs[j][cc] * wv;
    }
    float* dst = acc + ((size_t)side * MODV + s0) * FT_OUT + o;
#pragma unroll
    for (int j = 0; j < 4; j++) dst[(size_t)j * FT_OUT] = a[j];
}

// 4 rows per 256-thread block (one wave per row)
__global__ __launch_bounds__(256, 8)
void main_kernel(const int* __restrict__ stm, const int* __restrict__ nstm,
                 const float* __restrict__ vals,
                 const unsigned short* __restrict__ Wt,
                 const float* __restrict__ b_ft, const float* __restrict__ b_fft,
                 const float* __restrict__ fft_acc,
                 const float* __restrict__ W_out, const float* __restrict__ b_out,
                 float* __restrict__ out) {
    int w    = threadIdx.x >> 6;           // wave 0..3
    int lane = threadIdx.x & 63;
    int row  = blockIdx.x * 4 + w;

    __shared__ int   s_c[4][2][NNZ_PER];
    __shared__ float s_v[4][NNZ_PER];
    if (lane < NNZ_PER) {
        s_c[w][0][lane] = stm[NNZ + row * NNZ_PER + lane];
        s_v[w][lane]    = vals[row * NNZ_PER + lane];
    } else {
        int k = lane - NNZ_PER;
        s_c[w][1][k] = nstm[NNZ + row * NNZ_PER + k];
    }
    __syncthreads();

    float a0[8] = {0, 0, 0, 0, 0, 0, 0, 0};   // stm, features lane*8..lane*8+7
    float a1[8] = {0, 0, 0, 0, 0, 0, 0, 0};   // nstm

#pragma unroll 4
    for (int k = 0; k < NNZ_PER; k++) {
        float v = s_v[w][k];
        const uint4* p0 = (const uint4*)(Wt + (size_t)s_c[w][0][k] * FT_OUT);
        const uint4* p1 = (const uint4*)(Wt + (size_t)s_c[w][1][k] * FT_OUT);
        uint4 w0 = p0[lane];
        uint4 w1 = p1[lane];
        float e0, e1;
        unpack_bf16x2(w0.x, e0, e1); a0[0] += v * e0; a0[1] += v * e1;
        unpack_bf16x2(w0.y, e0, e1); a0[2] += v * e0; a0[3] += v * e1;
        unpack_bf16x2(w0.z, e0, e1); a0[4] += v * e0; a0[5] += v * e1;
        unpack_bf16x2(w0.w, e0, e1); a0[6] += v * e0; a0[7] += v * e1;
        unpack_bf16x2(w1.x, e0, e1); a1[0] += v * e0; a1[1] += v * e1;
        unpack_bf16x2(w1.y, e0, e1); a1[2] += v * e0; a1[3] += v * e1;
        unpack_bf16x2(w1.z, e0, e1); a1[4] += v * e0; a1[5] += v * e1;
        unpack_bf16x2(w1.w, e0, e1); a1[6] += v * e0; a1[7] += v * e1;
    }

    int ob = lane * 8;
    float bft[8], bff[8], wo0[8], wo1[8], fa0[8], fa1[8];
    *(float4*)&bft[0] = ((const float4*)(b_ft + ob))[0];
    *(float4*)&bft[4] = ((const float4*)(b_ft + ob))[1];
    *(float4*)&bff[0] = ((const float4*)(b_fft + ob))[0];
    *(float4*)&bff[4] = ((const float4*)(b_fft + ob))[1];
    *(float4*)&wo0[0] = ((const float4*)(W_out + ob))[0];
    *(float4*)&wo0[4] = ((const float4*)(W_out + ob))[1];
    *(float4*)&wo1[0] = ((const float4*)(W_out + FT_OUT + ob))[0];
    *(float4*)&wo1[4] = ((const float4*)(W_out + FT_OUT + ob))[1];
#pragma unroll
    for (int i = 0; i < 8; i++) { fa0[i] = 0.0f; fa1[i] = 0.0f; }
    if (row < MODV) {
        const float* p0 = fft_acc + (size_t)row * FT_OUT + ob;
        const float* p1 = fft_acc + (size_t)(MODV + row) * FT_OUT + ob;
        *(float4*)&fa0[0] = ((const float4*)p0)[0];
        *(float4*)&fa0[4] = ((const float4*)p0)[1];
        *(float4*)&fa1[0] = ((const float4*)p1)[0];
        *(float4*)&fa1[4] = ((const float4*)p1)[1];
    }

    float dot = 0.0f;
#pragma unroll
    for (int i = 0; i < 8; i++) {
        float h0 = clip01(a0[i] + bft[i] + bff[i] + fa0[i]);
        float h1 = clip01(a1[i] + bft[i] + bff[i] + fa1[i]);
        dot += h0 * wo0[i] + h1 * wo1[i];
    }

#pragma unroll
    for (int off = 32; off > 0; off >>= 1)
        dot += __shfl_down(dot, off, 64);

    if (lane == 0)
        out[row] = 1.0f / (1.0f + expf(-(dot + b_out[0])));
}

extern "C" void kernel_launch(void* const* d_in, const int* in_sizes, int n_in,
                              void* d_out, int out_size, void* d_ws, size_t ws_size,
                              hipStream_t stream) {
    const int*   stm   = (const int*)d_in[0];
    const int*   nstm  = (const int*)d_in[1];
    const float* vals  = (const float*)d_in[2];
    // d_in[3]: size scalar (compile-time B_SZ)
    const float* W_ft  = (const float*)d_in[4];
    const float* b_ft  = (const float*)d_in[5];
    const float* W_fft = (const float*)d_in[6];
    const float* b_fft = (const float*)d_in[7];
    const float* W_out = (const float*)d_in[8];
    const float* b_out = (const float*)d_in[9];
    float* out = (float*)d_out;

    unsigned short* Wt_bf = (unsigned short*)d_ws;                  // F_BIG*FT_OUT ushort
    float* Wfft_t  = (float*)(Wt_bf + (size_t)F_BIG * FT_OUT);      // MODV*FT_OUT
    float* H       = Wfft_t + (size_t)MODV * FT_OUT;                // 2*MODV*MODV
    float* fft_acc = H + (size_t)2 * MODV * MODV;                   // 2*MODV*FT_OUT

    (void)hipMemsetAsync(H, 0, (size_t)2 * MODV * MODV * sizeof(float), stream);

    prep_kernel<<<PREP_GRID, 256, 0, stream>>>(W_ft, W_fft, stm, nstm, vals,
                                               Wt_bf, Wfft_t, H);
    fft_gemm<<<320, 512, 0, stream>>>(H, Wfft_t, fft_acc);
    main_kernel<<<B_SZ / 4, 256, 0, stream>>>(stm, nstm, vals, Wt_bf, b_ft, b_fft,
                                              fft_acc, W_out, b_out, out);
}

// Round 6
// 395.402 us; speedup vs baseline: 1.0086x; 1.0086x over previous
//
#include <hip/hip_runtime.h>
#include <math.h>

#define B_SZ    16384
#define NNZ_PER 32
#define NNZ     (B_SZ * NNZ_PER)
#define FT_OUT  512
#define F_BIG   49152
#define F_SMALL 768
#define MODV    640

// prep grid partition
#define TP_A     1536              // W_ft tiles: 768 c-tiles(64) x 2 o-tiles(256)
#define TP_B     80                // W_fft 64x64 tiles: 8 ot x 10 ct
#define HISTB    512
#define PREP_GRID (TP_A + TP_B + HISTB)

// native clang vectors for nontemporal builtins (HIP_vector_type is rejected)
typedef unsigned int nuint4 __attribute__((ext_vector_type(4)));
typedef float        nfloat4 __attribute__((ext_vector_type(4)));

// ---------------------------------------------------------------------------
// ws layout:
//   Wt_bf   : F_BIG*FT_OUT ushort      48 MB  transposed big weight, bf16
//   Wfft_t  : MODV*FT_OUT float        1.3 MB transposed small weight (fp32)
//   H       : 2*MODV*MODV float        3.3 MB weighted histograms
//   fft_acc : 2*MODV*FT_OUT float      2.6 MB H @ Wfft^T (summed, per side)
// ---------------------------------------------------------------------------

__device__ __forceinline__ unsigned short f32_to_bf16_rne(float f) {
    union { float f; unsigned int u; } v; v.f = f;
    unsigned int u = v.u;
    return (unsigned short)((u + 0x7fffu + ((u >> 16) & 1u)) >> 16);
}

__device__ __forceinline__ void unpack_bf16x2(unsigned int u, float& lo, float& hi) {
    union { unsigned int i; float f; } a, b;
    a.i = u << 16;            // even element
    b.i = u & 0xffff0000u;    // odd element
    lo = a.f; hi = b.f;
}

__device__ __forceinline__ float clip01(float x) {
    return fminf(fmaxf(x, 0.0f), 1.0f);
}

// Fused prologue: transpose+bf16-quantize W_ft (64c x 256o tiles; bf16 LDS;
// 512B-contiguous nontemporal stores), transpose W_fft, mod-640 histogram.
__global__ __launch_bounds__(256)
void prep_kernel(const float* __restrict__ W_ft, const float* __restrict__ W_fft,
                 const int* __restrict__ stm, const int* __restrict__ nstm,
                 const float* __restrict__ vals,
                 unsigned short* __restrict__ Wt, float* __restrict__ Wfft_t,
                 float* __restrict__ H) {
    __shared__ __align__(16) unsigned char smem[256 * 68 * 2];   // 34.8 KB
    int b = blockIdx.x;
    int tid = threadIdx.x;
    if (b < TP_A) {
        // ---- W_ft transpose: tile c0..c0+63, o0..o0+255; LDS bf16 [o][c] ----
        unsigned short (*tA)[68] = (unsigned short (*)[68])smem;
        int ct = b >> 1, ot = b & 1;
        int c0 = ct * 64, o0 = ot * 256;
        int orow = tid >> 4, c4 = (tid & 15) * 4;
#pragma unroll
        for (int it = 0; it < 16; it++) {
            int oo = orow + it * 16;
            float4 f = *(const float4*)(W_ft + (size_t)(o0 + oo) * F_BIG + c0 + c4);
            tA[oo][c4 + 0] = f32_to_bf16_rne(f.x);
            tA[oo][c4 + 1] = f32_to_bf16_rne(f.y);
            tA[oo][c4 + 2] = f32_to_bf16_rne(f.z);
            tA[oo][c4 + 3] = f32_to_bf16_rne(f.w);
        }
        __syncthreads();
        // store: 64 c-rows x 256 bf16 (512 B contiguous) ; 32 lanes per c-row
        int ccb = tid >> 5, g = tid & 31;    // ccb 0..7, g = uint4 chunk in row
#pragma unroll
        for (int it = 0; it < 8; it++) {
            int cc = ccb + it * 8;
            nuint4 pk;
            unsigned int lo, hi;
            lo = tA[g * 8 + 0][cc]; hi = tA[g * 8 + 1][cc]; pk.x = lo | (hi << 16);
            lo = tA[g * 8 + 2][cc]; hi = tA[g * 8 + 3][cc]; pk.y = lo | (hi << 16);
            lo = tA[g * 8 + 4][cc]; hi = tA[g * 8 + 5][cc]; pk.z = lo | (hi << 16);
            lo = tA[g * 8 + 6][cc]; hi = tA[g * 8 + 7][cc]; pk.w = lo | (hi << 16);
            __builtin_nontemporal_store(pk,
                (nuint4*)(Wt + (size_t)(c0 + cc) * FT_OUT + o0 + g * 8));
        }
    } else if (b < TP_A + TP_B) {
        // ---- W_fft transpose: 64x64 fp32 tiles ----
        float (*tB)[65] = (float (*)[65])smem;
        int b2 = b - TP_A;
        int nct = MODV / 64;
        int ot = b2 / nct, ct = b2 % nct;
        int c0 = ct * 64, o0 = ot * 64;
        int rr = tid >> 4, c4 = (tid & 15) * 4;
#pragma unroll
        for (int it = 0; it < 4; it++) {
            int oo = rr + it * 16;
            float4 f = *(const float4*)(W_fft + (size_t)(o0 + oo) * F_SMALL + c0 + c4);
            tB[oo][c4 + 0] = f.x; tB[oo][c4 + 1] = f.y;
            tB[oo][c4 + 2] = f.z; tB[oo][c4 + 3] = f.w;
        }
        __syncthreads();
#pragma unroll
        for (int it = 0; it < 4; it++) {
            int idx = tid + it * 256;
            int cc = idx >> 4, g = idx & 15;
            nfloat4 v;
            v.x = tB[g * 4 + 0][cc]; v.y = tB[g * 4 + 1][cc];
            v.z = tB[g * 4 + 2][cc]; v.w = tB[g * 4 + 3][cc];
            __builtin_nontemporal_store(v,
                (nfloat4*)(Wfft_t + (size_t)(c0 + cc) * FT_OUT + o0 + g * 4));
        }
    } else {
        // ---- mod-640 weighted histogram ----
        int i0 = (b - TP_A - TP_B) * 256 + tid;
        for (int e = i0; e < 2 * NNZ; e += HISTB * 256) {
            int side = (e >= NNZ) ? 1 : 0;
            int j = e - side * NNZ;
            const int* arr = side ? nstm : stm;
            int r = arr[j] % MODV;          // row indices at offset 0
            int c = arr[NNZ + j] % MODV;    // col indices at offset NNZ
            atomicAdd(&H[(size_t)side * MODV * MODV + r * MODV + c], vals[j]);
        }
    }
}

// acc[side][s][o] = sum_cc H[side][s][cc] * Wfft_t[cc][o]
// grid = 2 sides x 160 s-tiles (4 rows each) = 320 blocks, full cc loop
__global__ __launch_bounds__(512)
void fft_gemm(const float* __restrict__ H, const float* __restrict__ Wfft_t,
              float* __restrict__ acc) {
    __shared__ float hs[4][MODV];
    int o = threadIdx.x;                 // 0..511
    int b = blockIdx.x;
    int side = b / 160;
    int s0   = (b % 160) * 4;
    const float* Hs = H + (size_t)side * MODV * MODV;
    for (int t = threadIdx.x; t < 4 * MODV; t += 512) {
        int j = t / MODV, cc = t - j * MODV;
        hs[j][cc] = Hs[(size_t)(s0 + j) * MODV + cc];
    }
    __syncthreads();
    float a[4] = {0, 0, 0, 0};
    for (int cc = 0; cc < MODV; cc++) {
        float wv = Wfft_t[(size_t)cc * FT_OUT + o];
#pragma unroll
        for (int j = 0; j < 4; j++) a[j] += hs[j][cc] * wv;
    }
    float* dst = acc + ((size_t)side * MODV + s0) * FT_OUT + o;
#pragma unroll
    for (int j = 0; j < 4; j++) dst[(size_t)j * FT_OUT] = a[j];
}

// one block (= one wave, 64 threads) per row — empirically fastest config (R2)
__global__ __launch_bounds__(64)
void main_kernel(const int* __restrict__ stm, const int* __restrict__ nstm,
                 const float* __restrict__ vals,
                 const unsigned short* __restrict__ Wt,
                 const float* __restrict__ b_ft, const float* __restrict__ b_fft,
                 const float* __restrict__ fft_acc,
                 const float* __restrict__ W_out, const float* __restrict__ b_out,
                 float* __restrict__ out) {
    int row = blockIdx.x;
    int tid = threadIdx.x;   // 0..63

    __shared__ int   s_c[2][NNZ_PER];
    __shared__ float s_v[NNZ_PER];
    if (tid < NNZ_PER) {
        s_c[0][tid] = stm[NNZ + row * NNZ_PER + tid];
        s_v[tid]    = vals[row * NNZ_PER + tid];
    } else {
        int k = tid - NNZ_PER;
        s_c[1][k] = nstm[NNZ + row * NNZ_PER + k];
    }
    __syncthreads();

    float a0[8] = {0, 0, 0, 0, 0, 0, 0, 0};   // stm, features tid*8..tid*8+7
    float a1[8] = {0, 0, 0, 0, 0, 0, 0, 0};   // nstm

#pragma unroll 4
    for (int k = 0; k < NNZ_PER; k++) {
        float v = s_v[k];
        const uint4* p0 = (const uint4*)(Wt + (size_t)s_c[0][k] * FT_OUT);
        const uint4* p1 = (const uint4*)(Wt + (size_t)s_c[1][k] * FT_OUT);
        uint4 w0 = p0[tid];
        uint4 w1 = p1[tid];
        float e0, e1;
        unpack_bf16x2(w0.x, e0, e1); a0[0] += v * e0; a0[1] += v * e1;
        unpack_bf16x2(w0.y, e0, e1); a0[2] += v * e0; a0[3] += v * e1;
        unpack_bf16x2(w0.z, e0, e1); a0[4] += v * e0; a0[5] += v * e1;
        unpack_bf16x2(w0.w, e0, e1); a0[6] += v * e0; a0[7] += v * e1;
        unpack_bf16x2(w1.x, e0, e1); a1[0] += v * e0; a1[1] += v * e1;
        unpack_bf16x2(w1.y, e0, e1); a1[2] += v * e0; a1[3] += v * e1;
        unpack_bf16x2(w1.z, e0, e1); a1[4] += v * e0; a1[5] += v * e1;
        unpack_bf16x2(w1.w, e0, e1); a1[6] += v * e0; a1[7] += v * e1;
    }

    int ob = tid * 8;
    float bft[8], bff[8], wo0[8], wo1[8], fa0[8], fa1[8];
    *(float4*)&bft[0] = ((const float4*)(b_ft + ob))[0];
    *(float4*)&bft[4] = ((const float4*)(b_ft + ob))[1];
    *(float4*)&bff[0] = ((const float4*)(b_fft + ob))[0];
    *(float4*)&bff[4] = ((const float4*)(b_fft + ob))[1];
    *(float4*)&wo0[0] = ((const float4*)(W_out + ob))[0];
    *(float4*)&wo0[4] = ((const float4*)(W_out + ob))[1];
    *(float4*)&wo1[0] = ((const float4*)(W_out + FT_OUT + ob))[0];
    *(float4*)&wo1[4] = ((const float4*)(W_out + FT_OUT + ob))[1];
#pragma unroll
    for (int i = 0; i < 8; i++) { fa0[i] = 0.0f; fa1[i] = 0.0f; }
    if (row < MODV) {
        const float* p0 = fft_acc + (size_t)row * FT_OUT + ob;
        const float* p1 = fft_acc + (size_t)(MODV + row) * FT_OUT + ob;
        *(float4*)&fa0[0] = ((const float4*)p0)[0];
        *(float4*)&fa0[4] = ((const float4*)p0)[1];
        *(float4*)&fa1[0] = ((const float4*)p1)[0];
        *(float4*)&fa1[4] = ((const float4*)p1)[1];
    }

    float dot = 0.0f;
#pragma unroll
    for (int i = 0; i < 8; i++) {
        float h0 = clip01(a0[i] + bft[i] + bff[i] + fa0[i]);
        float h1 = clip01(a1[i] + bft[i] + bff[i] + fa1[i]);
        dot += h0 * wo0[i] + h1 * wo1[i];
    }

#pragma unroll
    for (int off = 32; off > 0; off >>= 1)
        dot += __shfl_down(dot, off, 64);

    if (tid == 0)
        out[row] = 1.0f / (1.0f + expf(-(dot + b_out[0])));
}

extern "C" void kernel_launch(void* const* d_in, const int* in_sizes, int n_in,
                              void* d_out, int out_size, void* d_ws, size_t ws_size,
                              hipStream_t stream) {
    const int*   stm   = (const int*)d_in[0];
    const int*   nstm  = (const int*)d_in[1];
    const float* vals  = (const float*)d_in[2];
    // d_in[3]: size scalar (compile-time B_SZ)
    const float* W_ft  = (const float*)d_in[4];
    const float* b_ft  = (const float*)d_in[5];
    const float* W_fft = (const float*)d_in[6];
    const float* b_fft = (const float*)d_in[7];
    const float* W_out = (const float*)d_in[8];
    const float* b_out = (const float*)d_in[9];
    float* out = (float*)d_out;

    unsigned short* Wt_bf = (unsigned short*)d_ws;                  // F_BIG*FT_OUT ushort
    float* Wfft_t  = (float*)(Wt_bf + (size_t)F_BIG * FT_OUT);      // MODV*FT_OUT
    float* H       = Wfft_t + (size_t)MODV * FT_OUT;                // 2*MODV*MODV
    float* fft_acc = H + (size_t)2 * MODV * MODV;                   // 2*MODV*FT_OUT

    (void)hipMemsetAsync(H, 0, (size_t)2 * MODV * MODV * sizeof(float), stream);

    prep_kernel<<<PREP_GRID, 256, 0, stream>>>(W_ft, W_fft, stm, nstm, vals,
                                               Wt_bf, Wfft_t, H);
    fft_gemm<<<320, 512, 0, stream>>>(H, Wfft_t, fft_acc);
    main_kernel<<<B_SZ, 64, 0, stream>>>(stm, nstm, vals, Wt_bf, b_ft, b_fft,
                                         fft_acc, W_out, b_out, out);
}

// Round 7
// 389.606 us; speedup vs baseline: 1.0236x; 1.0149x over previous
//
#include <hip/hip_runtime.h>
#include <math.h>

#define B_SZ    16384
#define NNZ_PER 32
#define NNZ     (B_SZ * NNZ_PER)
#define FT_OUT  512
#define F_BIG   49152
#define F_SMALL 768
#define MODV    640

// prep grid partition
#define TP_A     1536              // W_ft tiles: 768 c-tiles(64) x 2 o-tiles(256)
#define TP_B     80                // W_fft 64x64 tiles: 8 ot x 10 ct
#define HISTB    512
#define PREP_GRID (TP_A + TP_B + HISTB)

// ---------------------------------------------------------------------------
// ws layout:
//   Wt_bf   : F_BIG*FT_OUT ushort      48 MB  transposed big weight, bf16
//   Wfft_t  : MODV*FT_OUT float        1.3 MB transposed small weight (fp32)
//   H       : 2*MODV*MODV float        3.3 MB weighted histograms
//   fft_acc : 2*MODV*FT_OUT float      2.6 MB H @ Wfft^T (summed, per side)
// ---------------------------------------------------------------------------

__device__ __forceinline__ unsigned short f32_to_bf16_rne(float f) {
    union { float f; unsigned int u; } v; v.f = f;
    unsigned int u = v.u;
    return (unsigned short)((u + 0x7fffu + ((u >> 16) & 1u)) >> 16);
}

__device__ __forceinline__ void unpack_bf16x2(unsigned int u, float& lo, float& hi) {
    union { unsigned int i; float f; } a, b;
    a.i = u << 16;            // even element
    b.i = u & 0xffff0000u;    // odd element
    lo = a.f; hi = b.f;
}

__device__ __forceinline__ float clip01(float x) {
    return fminf(fmaxf(x, 0.0f), 1.0f);
}

// Fused prologue: transpose+bf16-quantize W_ft, transpose W_fft, histogram.
// All stores CACHED (not nontemporal): Wt/Wfft_t are re-read by later kernels,
// NT in R6 evicted them from L3 and cost main ~5% (R2 vs R6 evidence).
__global__ __launch_bounds__(256)
void prep_kernel(const float* __restrict__ W_ft, const float* __restrict__ W_fft,
                 const int* __restrict__ stm, const int* __restrict__ nstm,
                 const float* __restrict__ vals,
                 unsigned short* __restrict__ Wt, float* __restrict__ Wfft_t,
                 float* __restrict__ H) {
    __shared__ __align__(16) unsigned char smem[256 * 68 * 2];   // 34.8 KB
    int b = blockIdx.x;
    int tid = threadIdx.x;
    if (b < TP_A) {
        // ---- W_ft transpose: tile c0..c0+63, o0..o0+255; LDS bf16 tA[o][c] ----
        unsigned short (*tA)[68] = (unsigned short (*)[68])smem;
        int ct = b >> 1, ot = b & 1;
        int c0 = ct * 64, o0 = ot * 256;
        int orow = tid >> 4, c4 = (tid & 15) * 4;
#pragma unroll
        for (int it = 0; it < 16; it++) {
            int oo = orow + it * 16;
            float4 f = *(const float4*)(W_ft + (size_t)(o0 + oo) * F_BIG + c0 + c4);
            tA[oo][c4 + 0] = f32_to_bf16_rne(f.x);
            tA[oo][c4 + 1] = f32_to_bf16_rne(f.y);
            tA[oo][c4 + 2] = f32_to_bf16_rne(f.z);
            tA[oo][c4 + 3] = f32_to_bf16_rne(f.w);
        }
        __syncthreads();
        // store v2: lane = column cc (stride-1 u16 LDS reads, conflict-free);
        // each lane emits 128 B contiguous (64 o) of its Wt row.
        int cc = tid & 63, och = tid >> 6;      // och 0..3
        int obase = och * 64;
        unsigned short* dst = Wt + (size_t)(c0 + cc) * FT_OUT + o0 + obase;
#pragma unroll
        for (int k = 0; k < 8; k++) {
            int o8 = obase + k * 8;
            uint4 pk;
            pk.x = (unsigned int)tA[o8 + 0][cc] | ((unsigned int)tA[o8 + 1][cc] << 16);
            pk.y = (unsigned int)tA[o8 + 2][cc] | ((unsigned int)tA[o8 + 3][cc] << 16);
            pk.z = (unsigned int)tA[o8 + 4][cc] | ((unsigned int)tA[o8 + 5][cc] << 16);
            pk.w = (unsigned int)tA[o8 + 6][cc] | ((unsigned int)tA[o8 + 7][cc] << 16);
            *(uint4*)(dst + k * 8) = pk;
        }
    } else if (b < TP_A + TP_B) {
        // ---- W_fft transpose: 64x64 fp32 tiles ----
        float (*tB)[65] = (float (*)[65])smem;
        int b2 = b - TP_A;
        int nct = MODV / 64;
        int ot = b2 / nct, ct = b2 % nct;
        int c0 = ct * 64, o0 = ot * 64;
        int rr = tid >> 4, c4 = (tid & 15) * 4;
#pragma unroll
        for (int it = 0; it < 4; it++) {
            int oo = rr + it * 16;
            float4 f = *(const float4*)(W_fft + (size_t)(o0 + oo) * F_SMALL + c0 + c4);
            tB[oo][c4 + 0] = f.x; tB[oo][c4 + 1] = f.y;
            tB[oo][c4 + 2] = f.z; tB[oo][c4 + 3] = f.w;
        }
        __syncthreads();
#pragma unroll
        for (int it = 0; it < 4; it++) {
            int idx = tid + it * 256;
            int cc = idx >> 4, g = idx & 15;
            float4 v = make_float4(tB[g * 4 + 0][cc], tB[g * 4 + 1][cc],
                                   tB[g * 4 + 2][cc], tB[g * 4 + 3][cc]);
            *(float4*)(Wfft_t + (size_t)(c0 + cc) * FT_OUT + o0 + g * 4) = v;
        }
    } else {
        // ---- mod-640 weighted histogram ----
        int i0 = (b - TP_A - TP_B) * 256 + tid;
        for (int e = i0; e < 2 * NNZ; e += HISTB * 256) {
            int side = (e >= NNZ) ? 1 : 0;
            int j = e - side * NNZ;
            const int* arr = side ? nstm : stm;
            int r = arr[j] % MODV;          // row indices at offset 0
            int c = arr[NNZ + j] % MODV;    // col indices at offset NNZ
            atomicAdd(&H[(size_t)side * MODV * MODV + r * MODV + c], vals[j]);
        }
    }
}

// acc[side][s][o] = sum_cc H[side][s][cc] * Wfft_t[cc][o]
// grid = 2 sides x 160 s-tiles (4 rows each) = 320 blocks, full cc loop
__global__ __launch_bounds__(512)
void fft_gemm(const float* __restrict__ H, const float* __restrict__ Wfft_t,
              float* __restrict__ acc) {
    __shared__ float hs[4][MODV];
    int o = threadIdx.x;                 // 0..511
    int b = blockIdx.x;
    int side = b / 160;
    int s0   = (b % 160) * 4;
    const float* Hs = H + (size_t)side * MODV * MODV;
    for (int t = threadIdx.x; t < 4 * MODV; t += 512) {
        int j = t / MODV, cc = t - j * MODV;
        hs[j][cc] = Hs[(size_t)(s0 + j) * MODV + cc];
    }
    __syncthreads();
    float a[4] = {0, 0, 0, 0};
    for (int cc = 0; cc < MODV; cc++) {
        float wv = Wfft_t[(size_t)cc * FT_OUT + o];
#pragma unroll
        for (int j = 0; j < 4; j++) a[j] += hs[j][cc] * wv;
    }
    float* dst = acc + ((size_t)side * MODV + s0) * FT_OUT + o;
#pragma unroll
    for (int j = 0; j < 4; j++) dst[(size_t)j * FT_OUT] = a[j];
}

// one block (= one wave, 64 threads) per row — empirically fastest config (R2)
__global__ __launch_bounds__(64)
void main_kernel(const int* __restrict__ stm, const int* __restrict__ nstm,
                 const float* __restrict__ vals,
                 const unsigned short* __restrict__ Wt,
                 const float* __restrict__ b_ft, const float* __restrict__ b_fft,
                 const float* __restrict__ fft_acc,
                 const float* __restrict__ W_out, const float* __restrict__ b_out,
                 float* __restrict__ out) {
    int row = blockIdx.x;
    int tid = threadIdx.x;   // 0..63

    __shared__ int   s_c[2][NNZ_PER];
    __shared__ float s_v[NNZ_PER];
    if (tid < NNZ_PER) {
        s_c[0][tid] = stm[NNZ + row * NNZ_PER + tid];
        s_v[tid]    = vals[row * NNZ_PER + tid];
    } else {
        int k = tid - NNZ_PER;
        s_c[1][k] = nstm[NNZ + row * NNZ_PER + k];
    }
    __syncthreads();

    float a0[8] = {0, 0, 0, 0, 0, 0, 0, 0};   // stm, features tid*8..tid*8+7
    float a1[8] = {0, 0, 0, 0, 0, 0, 0, 0};   // nstm

#pragma unroll 8
    for (int k = 0; k < NNZ_PER; k++) {
        float v = s_v[k];
        const uint4* p0 = (const uint4*)(Wt + (size_t)s_c[0][k] * FT_OUT);
        const uint4* p1 = (const uint4*)(Wt + (size_t)s_c[1][k] * FT_OUT);
        uint4 w0 = p0[tid];
        uint4 w1 = p1[tid];
        float e0, e1;
        unpack_bf16x2(w0.x, e0, e1); a0[0] += v * e0; a0[1] += v * e1;
        unpack_bf16x2(w0.y, e0, e1); a0[2] += v * e0; a0[3] += v * e1;
        unpack_bf16x2(w0.z, e0, e1); a0[4] += v * e0; a0[5] += v * e1;
        unpack_bf16x2(w0.w, e0, e1); a0[6] += v * e0; a0[7] += v * e1;
        unpack_bf16x2(w1.x, e0, e1); a1[0] += v * e0; a1[1] += v * e1;
        unpack_bf16x2(w1.y, e0, e1); a1[2] += v * e0; a1[3] += v * e1;
        unpack_bf16x2(w1.z, e0, e1); a1[4] += v * e0; a1[5] += v * e1;
        unpack_bf16x2(w1.w, e0, e1); a1[6] += v * e0; a1[7] += v * e1;
    }

    int ob = tid * 8;
    float bft[8], bff[8], wo0[8], wo1[8], fa0[8], fa1[8];
    *(float4*)&bft[0] = ((const float4*)(b_ft + ob))[0];
    *(float4*)&bft[4] = ((const float4*)(b_ft + ob))[1];
    *(float4*)&bff[0] = ((const float4*)(b_fft + ob))[0];
    *(float4*)&bff[4] = ((const float4*)(b_fft + ob))[1];
    *(float4*)&wo0[0] = ((const float4*)(W_out + ob))[0];
    *(float4*)&wo0[4] = ((const float4*)(W_out + ob))[1];
    *(float4*)&wo1[0] = ((const float4*)(W_out + FT_OUT + ob))[0];
    *(float4*)&wo1[4] = ((const float4*)(W_out + FT_OUT + ob))[1];
#pragma unroll
    for (int i = 0; i < 8; i++) { fa0[i] = 0.0f; fa1[i] = 0.0f; }
    if (row < MODV) {
        const float* p0 = fft_acc + (size_t)row * FT_OUT + ob;
        const float* p1 = fft_acc + (size_t)(MODV + row) * FT_OUT + ob;
        *(float4*)&fa0[0] = ((const float4*)p0)[0];
        *(float4*)&fa0[4] = ((const float4*)p0)[1];
        *(float4*)&fa1[0] = ((const float4*)p1)[0];
        *(float4*)&fa1[4] = ((const float4*)p1)[1];
    }

    float dot = 0.0f;
#pragma unroll
    for (int i = 0; i < 8; i++) {
        float h0 = clip01(a0[i] + bft[i] + bff[i] + fa0[i]);
        float h1 = clip01(a1[i] + bft[i] + bff[i] + fa1[i]);
        dot += h0 * wo0[i] + h1 * wo1[i];
    }

#pragma unroll
    for (int off = 32; off > 0; off >>= 1)
        dot += __shfl_down(dot, off, 64);

    if (tid == 0)
        out[row] = 1.0f / (1.0f + expf(-(dot + b_out[0])));
}

extern "C" void kernel_launch(void* const* d_in, const int* in_sizes, int n_in,
                              void* d_out, int out_size, void* d_ws, size_t ws_size,
                              hipStream_t stream) {
    const int*   stm   = (const int*)d_in[0];
    const int*   nstm  = (const int*)d_in[1];
    const float* vals  = (const float*)d_in[2];
    // d_in[3]: size scalar (compile-time B_SZ)
    const float* W_ft  = (const float*)d_in[4];
    const float* b_ft  = (const float*)d_in[5];
    const float* W_fft = (const float*)d_in[6];
    const float* b_fft = (const float*)d_in[7];
    const float* W_out = (const float*)d_in[8];
    const float* b_out = (const float*)d_in[9];
    float* out = (float*)d_out;

    unsigned short* Wt_bf = (unsigned short*)d_ws;                  // F_BIG*FT_OUT ushort
    float* Wfft_t  = (float*)(Wt_bf + (size_t)F_BIG * FT_OUT);      // MODV*FT_OUT
    float* H       = Wfft_t + (size_t)MODV * FT_OUT;                // 2*MODV*MODV
    float* fft_acc = H + (size_t)2 * MODV * MODV;                   // 2*MODV*FT_OUT

    (void)hipMemsetAsync(H, 0, (size_t)2 * MODV * MODV * sizeof(float), stream);

    prep_kernel<<<PREP_GRID, 256, 0, stream>>>(W_ft, W_fft, stm, nstm, vals,
                                               Wt_bf, Wfft_t, H);
    fft_gemm<<<320, 512, 0, stream>>>(H, Wfft_t, fft_acc);
    main_kernel<<<B_SZ, 64, 0, stream>>>(stm, nstm, vals, Wt_bf, b_ft, b_fft,
                                         fft_acc, W_out, b_out, out);
}